// Round 16
// baseline (373.201 us; speedup 1.0000x reference)
//
#include <hip/hip_runtime.h>
#include <hip/hip_bf16.h>
#include <math.h>

#define BATCH 4
#define NN 4096
#define DIN 128
#define DE 64
#define KK 16
#define CAP 512
#define GMAXF 2.9135f   // rigorous upper bound on f32 G = log(-log(q+1e-8))
#define GMINPAD 16.65f  // rigorous: G > -16.64 => lq < P + 16.64
#define SCRMARG 0.01f   // f32 compare slack
#define EPSA 0.5f       // rigorous bound on |P_mfma - P_golden| (est 0.13, 4x margin)

typedef __attribute__((ext_vector_type(8))) short bf16x8;   // 8 bf16 = 4 VGPR
typedef __attribute__((ext_vector_type(16))) float f32x16;  // MFMA 32x32 acc
typedef __attribute__((ext_vector_type(8))) short short8v;  // 8 f16 = 16 B

// ---------------- K1: xe = x @ W + bias (r7-verified) + bf16 hi/lo split ----------------
__global__ __launch_bounds__(256) void embed_kernel(
    const float* __restrict__ x, const float* __restrict__ W,
    const float* __restrict__ bias, float* __restrict__ xe,
    __hip_bfloat16* __restrict__ xeH, __hip_bfloat16* __restrict__ xeL) {
#pragma clang fp contract(off)
  __shared__ float wl[DIN][DE];
  __shared__ float xs[4][DIN];
  int t = threadIdx.x;
  for (int i = t * 4; i < DIN * DE; i += 1024)
    *(float4*)&wl[i >> 6][i & 63] = *(const float4*)&W[i];
  {
    int rr = t >> 6, dd = (t & 63) * 2;
    const float* src = x + ((size_t)blockIdx.x * 4 + rr) * DIN + dd;
    xs[rr][dd] = src[0];
    xs[rr][dd + 1] = src[1];
  }
  __syncthreads();
  int w = t >> 6, lane = t & 63;
  float acc = 0.f;
#pragma unroll
  for (int d = 0; d < DIN; ++d)
    acc = __builtin_fmaf(xs[w][d], wl[d][lane], acc);  // sequential FMA chain
  float r32 = acc + bias[lane];
  size_t o = ((size_t)blockIdx.x * 4 + w) * DE + lane;
  xe[o] = r32;
  __hip_bfloat16 h = __float2bfloat16(r32);
  float hf = __bfloat162float(h);
  xeH[o] = h;
  xeL[o] = __float2bfloat16(r32 - hf);
}

// numpy pairwise sum (n=64, scalar 8-accumulator path) of squares (r7-verified)
static __device__ __forceinline__ float np_pairwise_sq64(const float* a) {
#pragma clang fp contract(off)
  float p[8];
#pragma unroll
  for (int j = 0; j < 8; ++j) { float v = a[j]; p[j] = v * v; }
#pragma unroll
  for (int i = 8; i < 64; i += 8)
#pragma unroll
    for (int j = 0; j < 8; ++j) { float v = a[i + j]; p[j] = p[j] + v * v; }
  return ((p[0] + p[1]) + (p[2] + p[3])) + ((p[4] + p[5]) + (p[6] + p[7]));
}

__global__ __launch_bounds__(256) void sqnorm_kernel(
    const float* __restrict__ xe, float* __restrict__ sq) {
  int row = blockIdx.x * 256 + threadIdx.x;
  sq[row] = np_pairwise_sq64(xe + (size_t)row * DE);
}

// ---------------- K3: MFMA split-bf16 pass — u for ALL pairs -> f16 store + min2 ----------------
// Block = 128 rows x 256 cols, 4 waves. Fragment layout r14-verified.
// 3 indep acc chains; B double-buffered (r15-verified). Single pass:
// writes ustore[row][col] = (f16)u and per-(row,cb) min2 -> cellA.
__global__ __launch_bounds__(256, 1) void mfma_passA_kernel(
    const __hip_bfloat16* __restrict__ xeH,
    const __hip_bfloat16* __restrict__ xeL, const float* __restrict__ sq,
    float2* __restrict__ cellA, short* __restrict__ ustore) {
  int t = threadIdx.x;
  int w = t >> 6, lane = t & 63;
  int l31 = lane & 31, h = lane >> 5;
  int bid = (int)blockIdx.x;
  int cb = bid & 15;          // 256-col block
  int rb = (bid >> 4) & 31;   // 128-row tile
  int b = bid >> 9;           // batch
  int gr0 = (b << 12) + rb * 128 + w * 32;  // wave row base (global)
  int arow = gr0 + l31;

  bf16x8 aH[4], aL[4];
  {
    const __hip_bfloat16* pH = xeH + (size_t)arow * DE + h * 8;
    const __hip_bfloat16* pL = xeL + (size_t)arow * DE + h * 8;
#pragma unroll
    for (int ks = 0; ks < 4; ++ks) {
      aH[ks] = *(const bf16x8*)(const void*)(pH + ks * 16);
      aL[ks] = *(const bf16x8*)(const void*)(pL + ks * 16);
    }
  }

  float sqr[16];
  short* rowp[16];
#pragma unroll
  for (int i = 0; i < 16; ++i) {
    int ri = (i & 3) + 8 * (i >> 2) + 4 * h;
    sqr[i] = sq[gr0 + ri];
    rowp[i] = ustore + (size_t)(gr0 + ri) * NN + cb * 256 + l31;
  }

  float m1[16], m2[16];
#pragma unroll
  for (int i = 0; i < 16; ++i) { m1[i] = __builtin_inff(); m2[i] = __builtin_inff(); }

  bf16x8 BH[2][4], BL[2][4];
  float SQC[2];
#define LOADB(CT, SL)                                                           \
  {                                                                             \
    int colw_ = cb * 256 + (CT)*32 + l31;                                       \
    const __hip_bfloat16* pH_ = xeH + (size_t)((b << 12) + colw_) * DE + h * 8; \
    const __hip_bfloat16* pL_ = xeL + (size_t)((b << 12) + colw_) * DE + h * 8; \
    _Pragma("unroll") for (int ks = 0; ks < 4; ++ks) {                          \
      BH[SL][ks] = *(const bf16x8*)(const void*)(pH_ + ks * 16);                \
      BL[SL][ks] = *(const bf16x8*)(const void*)(pL_ + ks * 16);                \
    }                                                                           \
    SQC[SL] = sq[(b << 12) + colw_];                                            \
  }

  LOADB(0, 0)
#pragma unroll
  for (int ct = 0; ct < 8; ++ct) {
    int cur = ct & 1;
    if (ct < 7) LOADB(ct + 1, cur ^ 1)

    f32x16 aHH = {}, aHL = {}, aLH = {};
#pragma unroll
    for (int ks = 0; ks < 4; ++ks) {
      aHH = __builtin_amdgcn_mfma_f32_32x32x16_bf16(aH[ks], BH[cur][ks], aHH, 0, 0, 0);
      aHL = __builtin_amdgcn_mfma_f32_32x32x16_bf16(aH[ks], BL[cur][ks], aHL, 0, 0, 0);
      aLH = __builtin_amdgcn_mfma_f32_32x32x16_bf16(aL[ks], BH[cur][ks], aLH, 0, 0, 0);
    }

    float sqc = SQC[cur];
#pragma unroll
    for (int i = 0; i < 16; ++i) {
      float g = (aHH[i] + aHL[i]) + aLH[i];
      float u = (sqr[i] + sqc) - 2.0f * g;
      // f16 store of u (screen-side rounding padded into uthr)
      _Float16 hv = (_Float16)u;
      rowp[i][ct * 32] = __builtin_bit_cast(short, hv);
      // branchless min2
      float nm2 = fminf(fmaxf(u, m1[i]), m2[i]);
      m1[i] = fminf(u, m1[i]);
      m2[i] = nm2;
    }
  }
#undef LOADB

  // cross-lane min2 merge over the 32 lanes sharing h (r15-verified)
#pragma unroll
  for (int s = 1; s <= 16; s <<= 1) {
#pragma unroll
    for (int i = 0; i < 16; ++i) {
      float o1 = __shfl_xor(m1[i], s);
      float o2 = __shfl_xor(m2[i], s);
      float n1 = fminf(m1[i], o1);
      float n2 = fminf(fmaxf(m1[i], o1), fminf(m2[i], o2));
      m1[i] = n1;
      m2[i] = n2;
    }
  }
  if (l31 == 0) {
#pragma unroll
    for (int i = 0; i < 16; ++i) {
      int ri = (i & 3) + 8 * (i >> 2) + 4 * h;
      cellA[(size_t)(gr0 + ri) * 16 + cb] = make_float2(m1[i], m2[i]);
    }
  }
}

// ---------------- K4: uthr[row] from 16th-smallest u of cellA union ----------------
__global__ __launch_bounds__(256) void thr_kernel(
    const float2* __restrict__ cellA, const float* __restrict__ temp,
    float* __restrict__ uthr) {
  int row = (int)blockIdx.x * 256 + (int)threadIdx.x;
  float s32 = (float)exp(fmin(fmax((double)temp[0], -5.0), 5.0));
  const float2* cm = cellA + (size_t)row * 16;
  float tv[16];
#pragma unroll
  for (int k = 0; k < 16; ++k) tv[k] = __builtin_inff();
  for (int i = 0; i < 16; ++i) {
    float2 v2 = cm[i];
#pragma unroll
    for (int j = 0; j < 2; ++j) {
      float v = j ? v2.y : v2.x;
      if (v < tv[15]) {
#pragma unroll
        for (int k = 15; k >= 1; --k) {
          bool ltk = v < tv[k], ltk1 = v < tv[k - 1];
          tv[k] = ltk ? (ltk1 ? tv[k - 1] : v) : tv[k];
        }
        if (v < tv[0]) tv[0] = v;
      }
    }
  }
  // r15-verified pad stack (P-space) -> u-space, f64-division, round up;
  // + f16 screen pad (|uh-u| <= 2^-11|u|): +0.001|.|+0.002 (sound).
  float P16 = fmaxf(tv[15], 0.f) * s32;
  float T = P16 + (EPSA + GMINPAD + SCRMARG + EPSA + GMAXF);
  double ud = (double)T / (double)s32;
  float base = (float)(ud * 1.000002 + 1e-6);
  uthr[row] = base + 0.001f * fabsf(base) + 0.002f;
}

// ---------------- K5: scan ustore -> collect survivors -> exact rescore -> outputs ----------------
__global__ __launch_bounds__(64) void select_kernel(
    const short* __restrict__ ustore, const float* __restrict__ uthra,
    unsigned short* __restrict__ candC, const float* __restrict__ xe,
    const float* __restrict__ sq, const float* __restrict__ temp,
    const float* __restrict__ q, float* __restrict__ e0,
    float* __restrict__ e1, float* __restrict__ lp) {
#pragma clang fp contract(off)
  int row = (int)blockIdx.x * 64 + (int)threadIdx.x;
  int b = row >> 12, n = row & (NN - 1);
  float s32 = (float)exp(fmin(fmax((double)temp[0], -5.0), 5.0));
  float uthr = uthra[row];

  // phase 1: scan stored u (f16), collect survivor cols (cheap divergent body)
  const short8v* rp16 = (const short8v*)(ustore + (size_t)row * NN);
  unsigned short* lst = candC + (size_t)row * CAP;
  int cnt = 0;
  for (int j = 0; j < NN / 8; ++j) {
    short8v v = rp16[j];
    unsigned m = 0;
#pragma unroll
    for (int c = 0; c < 8; ++c) {
      _Float16 hv = __builtin_bit_cast(_Float16, (short)v[c]);
      m |= (unsigned)((float)hv < uthr) << c;
    }
    while (m) {
      int c = __builtin_ctz(m);
      m &= m - 1;
      if (cnt < CAP) lst[cnt] = (unsigned short)(j * 8 + c);
      cnt++;
    }
  }

  // phase 2: exact golden rescore (r7/r15-verified chain) on compact list
  float sqr = sq[row];
  const float* xb = xe + ((size_t)(b << 12)) * DE;
  const float* xr = xb + (size_t)n * DE;
  const float* sqb = sq + (b << 12);
  const float* qrow = q + ((size_t)b * NN + n) * NN;
  float tv[16];
  int ti[16];
#pragma unroll
  for (int k = 0; k < 16; ++k) { tv[k] = __builtin_inff(); ti[k] = 0x7FFFFFFF; }
  bool overflow = cnt > CAP;
  int lim = overflow ? NN : cnt;
  for (int i = 0; i < lim; ++i) {
    int col = overflow ? i : (int)lst[i];
    const float* xc = xb + (size_t)col * DE;
    float acc = 0.f;
#pragma unroll
    for (int d = 0; d < DE; ++d) acc = __builtin_fmaf(xr[d], xc[d], acc);
    float u = (sqr + sqb[col]) - 2.0f * acc;
    float P = fmaxf(u, 0.0f) * s32;
    if (P - GMAXF >= tv[15]) continue;  // sound: lq >= P - GMAXF
    float qv = qrow[col];
    float t1 = qv + 1e-8f;
    float l1 = (float)log((double)t1);  // correctly-rounded f32 log (r7-verified)
    float G = (float)log((double)(-l1));
    float lq = P - G;
    bool lt15 = (lq < tv[15]) || (lq == tv[15] && col < ti[15]);
    if (lt15) {
#pragma unroll
      for (int k = 15; k >= 1; --k) {
        bool ltk = (lq < tv[k]) || (lq == tv[k] && col < ti[k]);
        bool ltk1 = (lq < tv[k - 1]) || (lq == tv[k - 1] && col < ti[k - 1]);
        tv[k] = ltk ? (ltk1 ? tv[k - 1] : lq) : tv[k];
        ti[k] = ltk ? (ltk1 ? ti[k - 1] : col) : ti[k];
      }
      bool lt0 = (lq < tv[0]) || (lq == tv[0] && col < ti[0]);
      if (lt0) { tv[0] = lq; ti[0] = col; }
    }
  }
  size_t o = (size_t)row * KK;
#pragma unroll
  for (int k = 0; k < KK; ++k) {
    lp[o + k] = -tv[k];
    e0[o + k] = (float)(ti[k] + b * NN);
    e1[o + k] = (float)(n + b * NN);
  }
}

extern "C" void kernel_launch(void* const* d_in, const int* in_sizes, int n_in,
                              void* d_out, int out_size, void* d_ws,
                              size_t ws_size, hipStream_t stream) {
  (void)in_sizes; (void)n_in; (void)out_size; (void)ws_size;
  const float* x = (const float*)d_in[0];
  // d_in[1] = A (unused placeholder)
  const float* W = (const float*)d_in[2];
  const float* bias = (const float*)d_in[3];
  const float* temp = (const float*)d_in[4];
  const float* q = (const float*)d_in[5];

  float* xe = (float*)d_out;                 // [4,4096,64]
  float* e0 = xe + (size_t)BATCH * NN * DE;  // edges row 0 (indices)
  float* e1 = e0 + (size_t)BATCH * NN * KK;  // edges row 1 (rows)
  float* lp = e1 + (size_t)BATCH * NN * KK;  // logprobs

  const int ROWS = BATCH * NN;  // 16384
  char* ws = (char*)d_ws;
  float* sq = (float*)ws;                                  // 64 KB
  float* uthr = (float*)(ws + (64 << 10));                 // 64 KB
  float2* cellA = (float2*)(ws + (128 << 10));             // 2 MB
  char* p = ws + (128 << 10) + (size_t)ROWS * 16 * 8;
  __hip_bfloat16* xeH = (__hip_bfloat16*)p;                // 2 MB
  __hip_bfloat16* xeL = (__hip_bfloat16*)(p + (size_t)ROWS * DE * 2);  // 2 MB
  unsigned short* candC =
      (unsigned short*)(p + 2 * (size_t)ROWS * DE * 2);    // 16 MB
  short* ustore = (short*)(p + 2 * (size_t)ROWS * DE * 2 +
                           (size_t)ROWS * CAP * 2);        // 128 MB
  // total ~150 MB; ws_size proven >= 1 GiB (harness 0xAA fill = 1.074e9 B)

  embed_kernel<<<BATCH * NN / 4, 256, 0, stream>>>(x, W, bias, xe, xeH, xeL);
  sqnorm_kernel<<<ROWS / 256, 256, 0, stream>>>(xe, sq);
  mfma_passA_kernel<<<BATCH * 32 * 16, 256, 0, stream>>>(xeH, xeL, sq, cellA,
                                                         ustore);
  thr_kernel<<<ROWS / 256, 256, 0, stream>>>(cellA, temp, uthr);
  select_kernel<<<ROWS / 64, 64, 0, stream>>>(ustore, uthr, candC, xe, sq, temp,
                                              q, e0, e1, lp);
}

// Round 17
// 288.873 us; speedup vs baseline: 1.2919x; 1.2919x over previous
//
#include <hip/hip_runtime.h>
#include <hip/hip_bf16.h>
#include <math.h>

#define BATCH 4
#define NN 4096
#define DIN 128
#define DE 64
#define KK 16
#define CAP 512
#define GMAXF 2.9135f   // rigorous upper bound on f32 G = log(-log(q+1e-8))
#define GMINPAD 16.65f  // rigorous: G > -16.64 => lq < P + 16.64
#define SCRMARG 0.01f   // f32 compare slack
#define EPSA 0.5f       // rigorous bound on |P_mfma - P_golden| (est 0.13, 4x margin)

typedef __attribute__((ext_vector_type(8))) short bf16x8;   // 8 bf16 = 4 VGPR
typedef __attribute__((ext_vector_type(16))) float f32x16;  // MFMA 32x32 acc
typedef __attribute__((ext_vector_type(8))) short short8v;  // 8 f16 = 16 B

// ---------------- K1: xe = x @ W + bias (r7-verified) + bf16 hi/lo split ----------------
__global__ __launch_bounds__(256) void embed_kernel(
    const float* __restrict__ x, const float* __restrict__ W,
    const float* __restrict__ bias, float* __restrict__ xe,
    __hip_bfloat16* __restrict__ xeH, __hip_bfloat16* __restrict__ xeL) {
#pragma clang fp contract(off)
  __shared__ float wl[DIN][DE];
  __shared__ float xs[4][DIN];
  int t = threadIdx.x;
  for (int i = t * 4; i < DIN * DE; i += 1024)
    *(float4*)&wl[i >> 6][i & 63] = *(const float4*)&W[i];
  {
    int rr = t >> 6, dd = (t & 63) * 2;
    const float* src = x + ((size_t)blockIdx.x * 4 + rr) * DIN + dd;
    xs[rr][dd] = src[0];
    xs[rr][dd + 1] = src[1];
  }
  __syncthreads();
  int w = t >> 6, lane = t & 63;
  float acc = 0.f;
#pragma unroll
  for (int d = 0; d < DIN; ++d)
    acc = __builtin_fmaf(xs[w][d], wl[d][lane], acc);  // sequential FMA chain
  float r32 = acc + bias[lane];
  size_t o = ((size_t)blockIdx.x * 4 + w) * DE + lane;
  xe[o] = r32;
  __hip_bfloat16 h = __float2bfloat16(r32);
  float hf = __bfloat162float(h);
  xeH[o] = h;
  xeL[o] = __float2bfloat16(r32 - hf);
}

// numpy pairwise sum (n=64, scalar 8-accumulator path) of squares (r7-verified)
static __device__ __forceinline__ float np_pairwise_sq64(const float* a) {
#pragma clang fp contract(off)
  float p[8];
#pragma unroll
  for (int j = 0; j < 8; ++j) { float v = a[j]; p[j] = v * v; }
#pragma unroll
  for (int i = 8; i < 64; i += 8)
#pragma unroll
    for (int j = 0; j < 8; ++j) { float v = a[i + j]; p[j] = p[j] + v * v; }
  return ((p[0] + p[1]) + (p[2] + p[3])) + ((p[4] + p[5]) + (p[6] + p[7]));
}

__global__ __launch_bounds__(256) void sqnorm_kernel(
    const float* __restrict__ xe, float* __restrict__ sq) {
  int row = blockIdx.x * 256 + threadIdx.x;
  sq[row] = np_pairwise_sq64(xe + (size_t)row * DE);
}

// ---------------- K3: MFMA split-bf16 pass — u for ALL pairs -> f16 store + min2 ----------------
// (byte-identical to r16)
__global__ __launch_bounds__(256, 1) void mfma_passA_kernel(
    const __hip_bfloat16* __restrict__ xeH,
    const __hip_bfloat16* __restrict__ xeL, const float* __restrict__ sq,
    float2* __restrict__ cellA, short* __restrict__ ustore) {
  int t = threadIdx.x;
  int w = t >> 6, lane = t & 63;
  int l31 = lane & 31, h = lane >> 5;
  int bid = (int)blockIdx.x;
  int cb = bid & 15;
  int rb = (bid >> 4) & 31;
  int b = bid >> 9;
  int gr0 = (b << 12) + rb * 128 + w * 32;
  int arow = gr0 + l31;

  bf16x8 aH[4], aL[4];
  {
    const __hip_bfloat16* pH = xeH + (size_t)arow * DE + h * 8;
    const __hip_bfloat16* pL = xeL + (size_t)arow * DE + h * 8;
#pragma unroll
    for (int ks = 0; ks < 4; ++ks) {
      aH[ks] = *(const bf16x8*)(const void*)(pH + ks * 16);
      aL[ks] = *(const bf16x8*)(const void*)(pL + ks * 16);
    }
  }

  float sqr[16];
  short* rowp[16];
#pragma unroll
  for (int i = 0; i < 16; ++i) {
    int ri = (i & 3) + 8 * (i >> 2) + 4 * h;
    sqr[i] = sq[gr0 + ri];
    rowp[i] = ustore + (size_t)(gr0 + ri) * NN + cb * 256 + l31;
  }

  float m1[16], m2[16];
#pragma unroll
  for (int i = 0; i < 16; ++i) { m1[i] = __builtin_inff(); m2[i] = __builtin_inff(); }

  bf16x8 BH[2][4], BL[2][4];
  float SQC[2];
#define LOADB(CT, SL)                                                           \
  {                                                                             \
    int colw_ = cb * 256 + (CT)*32 + l31;                                       \
    const __hip_bfloat16* pH_ = xeH + (size_t)((b << 12) + colw_) * DE + h * 8; \
    const __hip_bfloat16* pL_ = xeL + (size_t)((b << 12) + colw_) * DE + h * 8; \
    _Pragma("unroll") for (int ks = 0; ks < 4; ++ks) {                          \
      BH[SL][ks] = *(const bf16x8*)(const void*)(pH_ + ks * 16);                \
      BL[SL][ks] = *(const bf16x8*)(const void*)(pL_ + ks * 16);                \
    }                                                                           \
    SQC[SL] = sq[(b << 12) + colw_];                                            \
  }

  LOADB(0, 0)
#pragma unroll
  for (int ct = 0; ct < 8; ++ct) {
    int cur = ct & 1;
    if (ct < 7) LOADB(ct + 1, cur ^ 1)

    f32x16 aHH = {}, aHL = {}, aLH = {};
#pragma unroll
    for (int ks = 0; ks < 4; ++ks) {
      aHH = __builtin_amdgcn_mfma_f32_32x32x16_bf16(aH[ks], BH[cur][ks], aHH, 0, 0, 0);
      aHL = __builtin_amdgcn_mfma_f32_32x32x16_bf16(aH[ks], BL[cur][ks], aHL, 0, 0, 0);
      aLH = __builtin_amdgcn_mfma_f32_32x32x16_bf16(aL[ks], BH[cur][ks], aLH, 0, 0, 0);
    }

    float sqc = SQC[cur];
#pragma unroll
    for (int i = 0; i < 16; ++i) {
      float g = (aHH[i] + aHL[i]) + aLH[i];
      float u = (sqr[i] + sqc) - 2.0f * g;
      _Float16 hv = (_Float16)u;
      rowp[i][ct * 32] = __builtin_bit_cast(short, hv);
      float nm2 = fminf(fmaxf(u, m1[i]), m2[i]);
      m1[i] = fminf(u, m1[i]);
      m2[i] = nm2;
    }
  }
#undef LOADB

#pragma unroll
  for (int s = 1; s <= 16; s <<= 1) {
#pragma unroll
    for (int i = 0; i < 16; ++i) {
      float o1 = __shfl_xor(m1[i], s);
      float o2 = __shfl_xor(m2[i], s);
      float n1 = fminf(m1[i], o1);
      float n2 = fminf(fmaxf(m1[i], o1), fminf(m2[i], o2));
      m1[i] = n1;
      m2[i] = n2;
    }
  }
  if (l31 == 0) {
#pragma unroll
    for (int i = 0; i < 16; ++i) {
      int ri = (i & 3) + 8 * (i >> 2) + 4 * h;
      cellA[(size_t)(gr0 + ri) * 16 + cb] = make_float2(m1[i], m2[i]);
    }
  }
}

// ---------------- K4: uthr[row] from 16th-smallest u of cellA union (r16-verified) ----------------
__global__ __launch_bounds__(256) void thr_kernel(
    const float2* __restrict__ cellA, const float* __restrict__ temp,
    float* __restrict__ uthr) {
  int row = (int)blockIdx.x * 256 + (int)threadIdx.x;
  float s32 = (float)exp(fmin(fmax((double)temp[0], -5.0), 5.0));
  const float2* cm = cellA + (size_t)row * 16;
  float tv[16];
#pragma unroll
  for (int k = 0; k < 16; ++k) tv[k] = __builtin_inff();
  for (int i = 0; i < 16; ++i) {
    float2 v2 = cm[i];
#pragma unroll
    for (int j = 0; j < 2; ++j) {
      float v = j ? v2.y : v2.x;
      if (v < tv[15]) {
#pragma unroll
        for (int k = 15; k >= 1; --k) {
          bool ltk = v < tv[k], ltk1 = v < tv[k - 1];
          tv[k] = ltk ? (ltk1 ? tv[k - 1] : v) : tv[k];
        }
        if (v < tv[0]) tv[0] = v;
      }
    }
  }
  float P16 = fmaxf(tv[15], 0.f) * s32;
  float T = P16 + (EPSA + GMINPAD + SCRMARG + EPSA + GMAXF);
  double ud = (double)T / (double)s32;
  float base = (float)(ud * 1.000002 + 1e-6);
  uthr[row] = base + 0.001f * fabsf(base) + 0.002f;
}

// order-preserving f32 -> u32 (lex key with col)
static __device__ __forceinline__ unsigned f2ord(float f) {
  unsigned u = __float_as_uint(f);
  return (u & 0x80000000u) ? ~u : (u | 0x80000000u);
}
static __device__ __forceinline__ float ord2f(unsigned u) {
  unsigned o = (u & 0x80000000u) ? (u & 0x7FFFFFFFu) : ~u;
  return __uint_as_float(o);
}

// ---------------- K5: wave-per-row scan + parallel rescore + u64-key top-16 ----------------
__global__ __launch_bounds__(256) void select_kernel(
    const short* __restrict__ ustore, const float* __restrict__ uthra,
    const float* __restrict__ xe, const float* __restrict__ sq,
    const float* __restrict__ temp, const float* __restrict__ q,
    float* __restrict__ e0, float* __restrict__ e1, float* __restrict__ lp) {
#pragma clang fp contract(off)
  __shared__ unsigned short lst_s[4][CAP];
  __shared__ float xr_s[4][DE];
  __shared__ int nch_s[4];

  int t = threadIdx.x;
  int w = t >> 6, lane = t & 63;
  int row = (int)blockIdx.x * 4 + w;
  int b = row >> 12, n = row & (NN - 1);
  float s32 = (float)exp(fmin(fmax((double)temp[0], -5.0), 5.0));
  float uthr = uthra[row];

  // stage row vector
  xr_s[w][lane] = xe[(size_t)row * DE + lane];

  // phase 1: coalesced scan of stored u (f16) + prefix-sum compaction
  const short8v* rp16 = (const short8v*)(ustore + (size_t)row * NN);
  int cnt = 0;
#pragma unroll
  for (int j = 0; j < 8; ++j) {
    short8v v = rp16[j * 64 + lane];
    unsigned m = 0;
#pragma unroll
    for (int c = 0; c < 8; ++c) {
      _Float16 hv = __builtin_bit_cast(_Float16, (short)v[c]);
      m |= (unsigned)((float)hv < uthr) << c;
    }
    int cntl = __builtin_popcount(m);
    int s = cntl;
#pragma unroll
    for (int off = 1; off < 64; off <<= 1) {
      int vv = __shfl_up(s, off);
      if (lane >= off) s += vv;
    }
    int pos = cnt + (s - cntl);
    int total = __shfl(s, 63);
    int basec = (j * 64 + lane) * 8;
    while (m) {
      int c = __builtin_ctz(m);
      m &= m - 1;
      if (pos < CAP) lst_s[w][pos] = (unsigned short)(basec + c);
      pos++;
    }
    cnt += total;
  }
  bool overflow = cnt > CAP;
  if (lane == 0) nch_s[w] = overflow ? (NN / 512) : 1;
  __syncthreads();
  int nch = max(max(nch_s[0], nch_s[1]), max(nch_s[2], nch_s[3]));

  // phase 2: rescore + u64-key top-16 (register-only extraction)
  float sqr = sq[row];
  const float* xb = xe + ((size_t)(b << 12)) * DE;
  const float* sqb = sq + (b << 12);
  const float* qrow = q + ((size_t)b * NN + n) * NN;
  const unsigned long long KMAX = ~0ULL;
  unsigned long long mykey = KMAX;  // lane k<16 ends holding k-th smallest
  int nitems = overflow ? NN : cnt;

  for (int ch = 0; ch < nch; ++ch) {
    unsigned long long ks[9];
#pragma unroll
    for (int s = 0; s < 8; ++s) {
      int idx = ch * 512 + s * 64 + lane;
      bool valid = idx < nitems;
      ks[s] = KMAX;
      if (__ballot(valid)) {
        int col = overflow ? idx : (valid ? (int)lst_s[w][idx] : 0);
        const float* xc = xb + (size_t)col * DE;
        float acc = 0.f;
#pragma unroll
        for (int d = 0; d < DE; ++d)
          acc = __builtin_fmaf(xr_s[w][d], xc[d], acc);  // golden seq-FMA
        float u = (sqr + sqb[col]) - 2.0f * acc;
        float P = fmaxf(u, 0.0f) * s32;
        float qv = qrow[col];
        float t1 = qv + 1e-8f;
        float l1 = (float)log((double)t1);  // CR f32 log (r7-verified)
        float G = (float)log((double)(-l1));
        float lq = P - G;
        if (valid)
          ks[s] = ((unsigned long long)f2ord(lq) << 32) | (unsigned)col;
      }
    }
    ks[8] = (lane < 16) ? mykey : KMAX;  // carry previous top-16
    mykey = KMAX;
#pragma unroll
    for (int r = 0; r < 16; ++r) {
      unsigned long long mn = ks[0];
#pragma unroll
      for (int s = 1; s < 9; ++s) mn = (ks[s] < mn) ? ks[s] : mn;
#pragma unroll
      for (int off = 1; off < 64; off <<= 1) {
        unsigned long long o = __shfl_xor(mn, off);
        mn = (o < mn) ? o : mn;
      }
      if (lane == r) mykey = mn;
#pragma unroll
      for (int s = 0; s < 9; ++s)
        if (ks[s] == mn) ks[s] = KMAX;
    }
  }

  if (lane < 16) {
    float lq = ord2f((unsigned)(mykey >> 32));
    int col = (int)(unsigned)(mykey & 0xFFFFFFFFu);
    size_t o = (size_t)row * KK + lane;
    lp[o] = -lq;
    e0[o] = (float)(col + b * NN);
    e1[o] = (float)(n + b * NN);
  }
}

extern "C" void kernel_launch(void* const* d_in, const int* in_sizes, int n_in,
                              void* d_out, int out_size, void* d_ws,
                              size_t ws_size, hipStream_t stream) {
  (void)in_sizes; (void)n_in; (void)out_size; (void)ws_size;
  const float* x = (const float*)d_in[0];
  // d_in[1] = A (unused placeholder)
  const float* W = (const float*)d_in[2];
  const float* bias = (const float*)d_in[3];
  const float* temp = (const float*)d_in[4];
  const float* q = (const float*)d_in[5];

  float* xe = (float*)d_out;                 // [4,4096,64]
  float* e0 = xe + (size_t)BATCH * NN * DE;  // edges row 0 (indices)
  float* e1 = e0 + (size_t)BATCH * NN * KK;  // edges row 1 (rows)
  float* lp = e1 + (size_t)BATCH * NN * KK;  // logprobs

  const int ROWS = BATCH * NN;  // 16384
  char* ws = (char*)d_ws;
  float* sq = (float*)ws;                                  // 64 KB
  float* uthr = (float*)(ws + (64 << 10));                 // 64 KB
  float2* cellA = (float2*)(ws + (128 << 10));             // 2 MB
  char* p = ws + (128 << 10) + (size_t)ROWS * 16 * 8;
  __hip_bfloat16* xeH = (__hip_bfloat16*)p;                // 2 MB
  __hip_bfloat16* xeL = (__hip_bfloat16*)(p + (size_t)ROWS * DE * 2);  // 2 MB
  short* ustore = (short*)(p + 2 * (size_t)ROWS * DE * 2); // 128 MB
  // total ~134 MB; ws_size proven >= 1 GiB (harness 0xAA fill)

  embed_kernel<<<BATCH * NN / 4, 256, 0, stream>>>(x, W, bias, xe, xeH, xeL);
  sqnorm_kernel<<<ROWS / 256, 256, 0, stream>>>(xe, sq);
  mfma_passA_kernel<<<BATCH * 32 * 16, 256, 0, stream>>>(xeH, xeL, sq, cellA,
                                                         ustore);
  thr_kernel<<<ROWS / 256, 256, 0, stream>>>(cellA, temp, uthr);
  select_kernel<<<ROWS / 4, 256, 0, stream>>>(ustore, uthr, xe, sq, temp, q, e0,
                                              e1, lp);
}

// Round 18
// 276.128 us; speedup vs baseline: 1.3515x; 1.0462x over previous
//
#include <hip/hip_runtime.h>
#include <hip/hip_bf16.h>
#include <math.h>

#define BATCH 4
#define NN 4096
#define DIN 128
#define DE 64
#define KK 16
#define CAP 512
#define GMAXF 2.9135f   // rigorous upper bound on f32 G = log(-log(q+1e-8))
#define GMINPAD 16.65f  // rigorous: G > -16.64 => lq < P + 16.64
#define SCRMARG 0.01f   // f32 compare slack
#define EPSA 0.5f       // rigorous bound on |P_mfma - P_golden| (est 0.13, 4x margin)

typedef __attribute__((ext_vector_type(8))) short bf16x8;   // 8 bf16 = 4 VGPR
typedef __attribute__((ext_vector_type(16))) float f32x16;  // MFMA 32x32 acc
typedef __attribute__((ext_vector_type(8))) short short8v;  // 8 f16 = 16 B

// ---------------- K1: xe = x @ W + bias (r7-verified) + bf16 hi/lo split ----------------
__global__ __launch_bounds__(256) void embed_kernel(
    const float* __restrict__ x, const float* __restrict__ W,
    const float* __restrict__ bias, float* __restrict__ xe,
    __hip_bfloat16* __restrict__ xeH, __hip_bfloat16* __restrict__ xeL) {
#pragma clang fp contract(off)
  __shared__ float wl[DIN][DE];
  __shared__ float xs[4][DIN];
  int t = threadIdx.x;
  for (int i = t * 4; i < DIN * DE; i += 1024)
    *(float4*)&wl[i >> 6][i & 63] = *(const float4*)&W[i];
  {
    int rr = t >> 6, dd = (t & 63) * 2;
    const float* src = x + ((size_t)blockIdx.x * 4 + rr) * DIN + dd;
    xs[rr][dd] = src[0];
    xs[rr][dd + 1] = src[1];
  }
  __syncthreads();
  int w = t >> 6, lane = t & 63;
  float acc = 0.f;
#pragma unroll
  for (int d = 0; d < DIN; ++d)
    acc = __builtin_fmaf(xs[w][d], wl[d][lane], acc);  // sequential FMA chain
  float r32 = acc + bias[lane];
  size_t o = ((size_t)blockIdx.x * 4 + w) * DE + lane;
  xe[o] = r32;
  __hip_bfloat16 h = __float2bfloat16(r32);
  float hf = __bfloat162float(h);
  xeH[o] = h;
  xeL[o] = __float2bfloat16(r32 - hf);
}

// numpy pairwise sum (n=64, scalar 8-accumulator path) of squares (r7-verified)
static __device__ __forceinline__ float np_pairwise_sq64(const float* a) {
#pragma clang fp contract(off)
  float p[8];
#pragma unroll
  for (int j = 0; j < 8; ++j) { float v = a[j]; p[j] = v * v; }
#pragma unroll
  for (int i = 8; i < 64; i += 8)
#pragma unroll
    for (int j = 0; j < 8; ++j) { float v = a[i + j]; p[j] = p[j] + v * v; }
  return ((p[0] + p[1]) + (p[2] + p[3])) + ((p[4] + p[5]) + (p[6] + p[7]));
}

__global__ __launch_bounds__(256) void sqnorm_kernel(
    const float* __restrict__ xe, float* __restrict__ sq) {
  int row = blockIdx.x * 256 + threadIdx.x;
  sq[row] = np_pairwise_sq64(xe + (size_t)row * DE);
}

// ---------------- K3: MFMA split-bf16 pass — u for ALL pairs -> f16 store + min2 ----------------
// (byte-identical to r16/r17)
__global__ __launch_bounds__(256, 1) void mfma_passA_kernel(
    const __hip_bfloat16* __restrict__ xeH,
    const __hip_bfloat16* __restrict__ xeL, const float* __restrict__ sq,
    float2* __restrict__ cellA, short* __restrict__ ustore) {
  int t = threadIdx.x;
  int w = t >> 6, lane = t & 63;
  int l31 = lane & 31, h = lane >> 5;
  int bid = (int)blockIdx.x;
  int cb = bid & 15;
  int rb = (bid >> 4) & 31;
  int b = bid >> 9;
  int gr0 = (b << 12) + rb * 128 + w * 32;
  int arow = gr0 + l31;

  bf16x8 aH[4], aL[4];
  {
    const __hip_bfloat16* pH = xeH + (size_t)arow * DE + h * 8;
    const __hip_bfloat16* pL = xeL + (size_t)arow * DE + h * 8;
#pragma unroll
    for (int ks = 0; ks < 4; ++ks) {
      aH[ks] = *(const bf16x8*)(const void*)(pH + ks * 16);
      aL[ks] = *(const bf16x8*)(const void*)(pL + ks * 16);
    }
  }

  float sqr[16];
  short* rowp[16];
#pragma unroll
  for (int i = 0; i < 16; ++i) {
    int ri = (i & 3) + 8 * (i >> 2) + 4 * h;
    sqr[i] = sq[gr0 + ri];
    rowp[i] = ustore + (size_t)(gr0 + ri) * NN + cb * 256 + l31;
  }

  float m1[16], m2[16];
#pragma unroll
  for (int i = 0; i < 16; ++i) { m1[i] = __builtin_inff(); m2[i] = __builtin_inff(); }

  bf16x8 BH[2][4], BL[2][4];
  float SQC[2];
#define LOADB(CT, SL)                                                           \
  {                                                                             \
    int colw_ = cb * 256 + (CT)*32 + l31;                                       \
    const __hip_bfloat16* pH_ = xeH + (size_t)((b << 12) + colw_) * DE + h * 8; \
    const __hip_bfloat16* pL_ = xeL + (size_t)((b << 12) + colw_) * DE + h * 8; \
    _Pragma("unroll") for (int ks = 0; ks < 4; ++ks) {                          \
      BH[SL][ks] = *(const bf16x8*)(const void*)(pH_ + ks * 16);                \
      BL[SL][ks] = *(const bf16x8*)(const void*)(pL_ + ks * 16);                \
    }                                                                           \
    SQC[SL] = sq[(b << 12) + colw_];                                            \
  }

  LOADB(0, 0)
#pragma unroll
  for (int ct = 0; ct < 8; ++ct) {
    int cur = ct & 1;
    if (ct < 7) LOADB(ct + 1, cur ^ 1)

    f32x16 aHH = {}, aHL = {}, aLH = {};
#pragma unroll
    for (int ks = 0; ks < 4; ++ks) {
      aHH = __builtin_amdgcn_mfma_f32_32x32x16_bf16(aH[ks], BH[cur][ks], aHH, 0, 0, 0);
      aHL = __builtin_amdgcn_mfma_f32_32x32x16_bf16(aH[ks], BL[cur][ks], aHL, 0, 0, 0);
      aLH = __builtin_amdgcn_mfma_f32_32x32x16_bf16(aL[ks], BH[cur][ks], aLH, 0, 0, 0);
    }

    float sqc = SQC[cur];
#pragma unroll
    for (int i = 0; i < 16; ++i) {
      float g = (aHH[i] + aHL[i]) + aLH[i];
      float u = (sqr[i] + sqc) - 2.0f * g;
      _Float16 hv = (_Float16)u;
      rowp[i][ct * 32] = __builtin_bit_cast(short, hv);
      float nm2 = fminf(fmaxf(u, m1[i]), m2[i]);
      m1[i] = fminf(u, m1[i]);
      m2[i] = nm2;
    }
  }
#undef LOADB

#pragma unroll
  for (int s = 1; s <= 16; s <<= 1) {
#pragma unroll
    for (int i = 0; i < 16; ++i) {
      float o1 = __shfl_xor(m1[i], s);
      float o2 = __shfl_xor(m2[i], s);
      float n1 = fminf(m1[i], o1);
      float n2 = fminf(fmaxf(m1[i], o1), fminf(m2[i], o2));
      m1[i] = n1;
      m2[i] = n2;
    }
  }
  if (l31 == 0) {
#pragma unroll
    for (int i = 0; i < 16; ++i) {
      int ri = (i & 3) + 8 * (i >> 2) + 4 * h;
      cellA[(size_t)(gr0 + ri) * 16 + cb] = make_float2(m1[i], m2[i]);
    }
  }
}

// ---------------- K4: uthr[row] from 16th-smallest u of cellA union (r16-verified) ----------------
__global__ __launch_bounds__(256) void thr_kernel(
    const float2* __restrict__ cellA, const float* __restrict__ temp,
    float* __restrict__ uthr) {
  int row = (int)blockIdx.x * 256 + (int)threadIdx.x;
  float s32 = (float)exp(fmin(fmax((double)temp[0], -5.0), 5.0));
  const float2* cm = cellA + (size_t)row * 16;
  float tv[16];
#pragma unroll
  for (int k = 0; k < 16; ++k) tv[k] = __builtin_inff();
  for (int i = 0; i < 16; ++i) {
    float2 v2 = cm[i];
#pragma unroll
    for (int j = 0; j < 2; ++j) {
      float v = j ? v2.y : v2.x;
      if (v < tv[15]) {
#pragma unroll
        for (int k = 15; k >= 1; --k) {
          bool ltk = v < tv[k], ltk1 = v < tv[k - 1];
          tv[k] = ltk ? (ltk1 ? tv[k - 1] : v) : tv[k];
        }
        if (v < tv[0]) tv[0] = v;
      }
    }
  }
  float P16 = fmaxf(tv[15], 0.f) * s32;
  float T = P16 + (EPSA + GMINPAD + SCRMARG + EPSA + GMAXF);
  double ud = (double)T / (double)s32;
  float base = (float)(ud * 1.000002 + 1e-6);
  uthr[row] = base + 0.001f * fabsf(base) + 0.002f;
}

// order-preserving f32 -> u32 (lex key with col)
static __device__ __forceinline__ unsigned f2ord(float f) {
  unsigned u = __float_as_uint(f);
  return (u & 0x80000000u) ? ~u : (u | 0x80000000u);
}
static __device__ __forceinline__ float ord2f(unsigned u) {
  unsigned o = (u & 0x80000000u) ? (u & 0x7FFFFFFFu) : ~u;
  return __uint_as_float(o);
}

// ---------------- K5: block-per-row scan (LDS-atomic compact) + rescore + top-16 ----------------
__global__ __launch_bounds__(256) void select_kernel(
    const short* __restrict__ ustore, const float* __restrict__ uthra,
    const float* __restrict__ xe, const float* __restrict__ sq,
    const float* __restrict__ temp, const float* __restrict__ q,
    float* __restrict__ e0, float* __restrict__ e1, float* __restrict__ lp) {
#pragma clang fp contract(off)
  __shared__ unsigned short lst_s[CAP];
  __shared__ unsigned long long keys_s[512];
  __shared__ float xr_s[DE];
  __shared__ int lcnt_s;

  int t = threadIdx.x;
  int w = t >> 6, lane = t & 63;
  int row = (int)blockIdx.x;
  int b = row >> 12, n = row & (NN - 1);
  float s32 = (float)exp(fmin(fmax((double)temp[0], -5.0), 5.0));
  float uthr = uthra[row];

  if (t < DE) xr_s[t] = xe[(size_t)row * DE + t];
  if (t == 0) lcnt_s = 0;
  __syncthreads();

  // phase 1: coalesced scan, LDS-atomic compaction (order-free: keys sort later)
  const short8v* rp16 = (const short8v*)(ustore + (size_t)row * NN);
#pragma unroll
  for (int r = 0; r < 2; ++r) {
    int idx = r * 256 + t;  // short8v index in [0,512)
    short8v v = rp16[idx];
    unsigned m = 0;
#pragma unroll
    for (int c = 0; c < 8; ++c) {
      _Float16 hv = __builtin_bit_cast(_Float16, (short)v[c]);
      m |= (unsigned)((float)hv < uthr) << c;
    }
    while (m) {
      int c = __builtin_ctz(m);
      m &= m - 1;
      int pos = atomicAdd(&lcnt_s, 1);
      if (pos < CAP) lst_s[pos] = (unsigned short)(idx * 8 + c);
    }
  }
  __syncthreads();
  int cnt = lcnt_s;
  bool overflow = cnt > CAP;
  int nitems = overflow ? NN : cnt;
  int nch = overflow ? (NN / 512) : 1;

  // phase 2: rescore (golden chain) into LDS keys; wave-0 u64 top-16 extraction
  float sqr = sq[row];
  const float* xb = xe + ((size_t)(b << 12)) * DE;
  const float* sqb = sq + (b << 12);
  const float* qrow = q + ((size_t)b * NN + n) * NN;
  const unsigned long long KMAX = ~0ULL;
  unsigned long long mykey = KMAX;  // wave 0, lane k<16: k-th smallest so far

  for (int ch = 0; ch < nch; ++ch) {
#pragma unroll
    for (int rsub = 0; rsub < 2; ++rsub) {
      int gi = ch * 512 + rsub * 256 + t;
      unsigned long long key = KMAX;
      if (gi < nitems) {
        int col = overflow ? gi : (int)lst_s[gi];
        const float* xc = xb + (size_t)col * DE;
        float acc = 0.f;
#pragma unroll
        for (int d = 0; d < DE; ++d)
          acc = __builtin_fmaf(xr_s[d], xc[d], acc);  // golden seq-FMA
        float u = (sqr + sqb[col]) - 2.0f * acc;
        float P = fmaxf(u, 0.0f) * s32;
        float qv = qrow[col];
        float t1 = qv + 1e-8f;
        float l1 = (float)log((double)t1);  // CR f32 log (r7-verified)
        float G = (float)log((double)(-l1));
        float lq = P - G;
        key = ((unsigned long long)f2ord(lq) << 32) | (unsigned)col;
      }
      keys_s[rsub * 256 + t] = key;
    }
    __syncthreads();
    if (w == 0) {
      unsigned long long ks[9];
#pragma unroll
      for (int s = 0; s < 8; ++s) ks[s] = keys_s[s * 64 + lane];
      ks[8] = (lane < 16) ? mykey : KMAX;  // carry
      mykey = KMAX;
#pragma unroll
      for (int r = 0; r < 16; ++r) {
        unsigned long long mn = ks[0];
#pragma unroll
        for (int s = 1; s < 9; ++s) mn = (ks[s] < mn) ? ks[s] : mn;
#pragma unroll
        for (int off = 1; off < 64; off <<= 1) {
          unsigned long long o = __shfl_xor(mn, off);
          mn = (o < mn) ? o : mn;
        }
        if (lane == r) mykey = mn;
#pragma unroll
        for (int s = 0; s < 9; ++s)
          if (ks[s] == mn) ks[s] = KMAX;
      }
    }
    __syncthreads();
  }

  if (w == 0 && lane < 16) {
    float lq = ord2f((unsigned)(mykey >> 32));
    int col = (int)(unsigned)(mykey & 0xFFFFFFFFu);
    size_t o = (size_t)row * KK + lane;
    lp[o] = -lq;
    e0[o] = (float)(col + b * NN);
    e1[o] = (float)(n + b * NN);
  }
}

extern "C" void kernel_launch(void* const* d_in, const int* in_sizes, int n_in,
                              void* d_out, int out_size, void* d_ws,
                              size_t ws_size, hipStream_t stream) {
  (void)in_sizes; (void)n_in; (void)out_size; (void)ws_size;
  const float* x = (const float*)d_in[0];
  // d_in[1] = A (unused placeholder)
  const float* W = (const float*)d_in[2];
  const float* bias = (const float*)d_in[3];
  const float* temp = (const float*)d_in[4];
  const float* q = (const float*)d_in[5];

  float* xe = (float*)d_out;                 // [4,4096,64]
  float* e0 = xe + (size_t)BATCH * NN * DE;  // edges row 0 (indices)
  float* e1 = e0 + (size_t)BATCH * NN * KK;  // edges row 1 (rows)
  float* lp = e1 + (size_t)BATCH * NN * KK;  // logprobs

  const int ROWS = BATCH * NN;  // 16384
  char* ws = (char*)d_ws;
  float* sq = (float*)ws;                                  // 64 KB
  float* uthr = (float*)(ws + (64 << 10));                 // 64 KB
  float2* cellA = (float2*)(ws + (128 << 10));             // 2 MB
  char* p = ws + (128 << 10) + (size_t)ROWS * 16 * 8;
  __hip_bfloat16* xeH = (__hip_bfloat16*)p;                // 2 MB
  __hip_bfloat16* xeL = (__hip_bfloat16*)(p + (size_t)ROWS * DE * 2);  // 2 MB
  short* ustore = (short*)(p + 2 * (size_t)ROWS * DE * 2); // 128 MB
  // total ~134 MB; ws_size proven >= 1 GiB (harness 0xAA fill)

  embed_kernel<<<BATCH * NN / 4, 256, 0, stream>>>(x, W, bias, xe, xeH, xeL);
  sqnorm_kernel<<<ROWS / 256, 256, 0, stream>>>(xe, sq);
  mfma_passA_kernel<<<BATCH * 32 * 16, 256, 0, stream>>>(xeH, xeL, sq, cellA,
                                                         ustore);
  thr_kernel<<<ROWS / 256, 256, 0, stream>>>(cellA, temp, uthr);
  select_kernel<<<ROWS, 256, 0, stream>>>(ustore, uthr, xe, sq, temp, q, e0, e1,
                                          lp);
}

// Round 19
// 188.694 us; speedup vs baseline: 1.9778x; 1.4634x over previous
//
#include <hip/hip_runtime.h>
#include <hip/hip_bf16.h>
#include <math.h>

#define BATCH 4
#define NN 4096
#define DIN 128
#define DE 64
#define KK 16
#define CAP 512
#define GMAXF 2.9135f   // rigorous upper bound on f32 G = log(-log(q+1e-8))
#define GMINPAD 16.65f  // rigorous: G > -16.64 => lq < P + 16.64
#define SCRMARG 0.01f   // f32 compare slack
#define EPSA 0.5f       // rigorous bound on |P_mfma - P_golden| (est 0.13, 4x margin)

typedef __attribute__((ext_vector_type(8))) short bf16x8;   // 8 bf16 = 4 VGPR
typedef __attribute__((ext_vector_type(16))) float f32x16;  // MFMA 32x32 acc
typedef __attribute__((ext_vector_type(8))) short short8v;  // 8 f16 = 16 B

// ---------------- K1: xe = x @ W + bias (r7-verified) + bf16 hi/lo split ----------------
__global__ __launch_bounds__(256) void embed_kernel(
    const float* __restrict__ x, const float* __restrict__ W,
    const float* __restrict__ bias, float* __restrict__ xe,
    __hip_bfloat16* __restrict__ xeH, __hip_bfloat16* __restrict__ xeL) {
#pragma clang fp contract(off)
  __shared__ float wl[DIN][DE];
  __shared__ float xs[4][DIN];
  int t = threadIdx.x;
  for (int i = t * 4; i < DIN * DE; i += 1024)
    *(float4*)&wl[i >> 6][i & 63] = *(const float4*)&W[i];
  {
    int rr = t >> 6, dd = (t & 63) * 2;
    const float* src = x + ((size_t)blockIdx.x * 4 + rr) * DIN + dd;
    xs[rr][dd] = src[0];
    xs[rr][dd + 1] = src[1];
  }
  __syncthreads();
  int w = t >> 6, lane = t & 63;
  float acc = 0.f;
#pragma unroll
  for (int d = 0; d < DIN; ++d)
    acc = __builtin_fmaf(xs[w][d], wl[d][lane], acc);  // sequential FMA chain
  float r32 = acc + bias[lane];
  size_t o = ((size_t)blockIdx.x * 4 + w) * DE + lane;
  xe[o] = r32;
  __hip_bfloat16 h = __float2bfloat16(r32);
  float hf = __bfloat162float(h);
  xeH[o] = h;
  xeL[o] = __float2bfloat16(r32 - hf);
}

// numpy pairwise sum (n=64, scalar 8-accumulator path) of squares (r7-verified)
static __device__ __forceinline__ float np_pairwise_sq64(const float* a) {
#pragma clang fp contract(off)
  float p[8];
#pragma unroll
  for (int j = 0; j < 8; ++j) { float v = a[j]; p[j] = v * v; }
#pragma unroll
  for (int i = 8; i < 64; i += 8)
#pragma unroll
    for (int j = 0; j < 8; ++j) { float v = a[i + j]; p[j] = p[j] + v * v; }
  return ((p[0] + p[1]) + (p[2] + p[3])) + ((p[4] + p[5]) + (p[6] + p[7]));
}

__global__ __launch_bounds__(256) void sqnorm_kernel(
    const float* __restrict__ xe, float* __restrict__ sq) {
  int row = blockIdx.x * 256 + threadIdx.x;
  sq[row] = np_pairwise_sq64(xe + (size_t)row * DE);
}

// ---------------- K3: MFMA split-bf16 pass — u for ALL pairs -> f16 store + min2 ----------------
// (byte-identical to r16/r17/r18)
__global__ __launch_bounds__(256, 1) void mfma_passA_kernel(
    const __hip_bfloat16* __restrict__ xeH,
    const __hip_bfloat16* __restrict__ xeL, const float* __restrict__ sq,
    float2* __restrict__ cellA, short* __restrict__ ustore) {
  int t = threadIdx.x;
  int w = t >> 6, lane = t & 63;
  int l31 = lane & 31, h = lane >> 5;
  int bid = (int)blockIdx.x;
  int cb = bid & 15;
  int rb = (bid >> 4) & 31;
  int b = bid >> 9;
  int gr0 = (b << 12) + rb * 128 + w * 32;
  int arow = gr0 + l31;

  bf16x8 aH[4], aL[4];
  {
    const __hip_bfloat16* pH = xeH + (size_t)arow * DE + h * 8;
    const __hip_bfloat16* pL = xeL + (size_t)arow * DE + h * 8;
#pragma unroll
    for (int ks = 0; ks < 4; ++ks) {
      aH[ks] = *(const bf16x8*)(const void*)(pH + ks * 16);
      aL[ks] = *(const bf16x8*)(const void*)(pL + ks * 16);
    }
  }

  float sqr[16];
  short* rowp[16];
#pragma unroll
  for (int i = 0; i < 16; ++i) {
    int ri = (i & 3) + 8 * (i >> 2) + 4 * h;
    sqr[i] = sq[gr0 + ri];
    rowp[i] = ustore + (size_t)(gr0 + ri) * NN + cb * 256 + l31;
  }

  float m1[16], m2[16];
#pragma unroll
  for (int i = 0; i < 16; ++i) { m1[i] = __builtin_inff(); m2[i] = __builtin_inff(); }

  bf16x8 BH[2][4], BL[2][4];
  float SQC[2];
#define LOADB(CT, SL)                                                           \
  {                                                                             \
    int colw_ = cb * 256 + (CT)*32 + l31;                                       \
    const __hip_bfloat16* pH_ = xeH + (size_t)((b << 12) + colw_) * DE + h * 8; \
    const __hip_bfloat16* pL_ = xeL + (size_t)((b << 12) + colw_) * DE + h * 8; \
    _Pragma("unroll") for (int ks = 0; ks < 4; ++ks) {                          \
      BH[SL][ks] = *(const bf16x8*)(const void*)(pH_ + ks * 16);                \
      BL[SL][ks] = *(const bf16x8*)(const void*)(pL_ + ks * 16);                \
    }                                                                           \
    SQC[SL] = sq[(b << 12) + colw_];                                            \
  }

  LOADB(0, 0)
#pragma unroll
  for (int ct = 0; ct < 8; ++ct) {
    int cur = ct & 1;
    if (ct < 7) LOADB(ct + 1, cur ^ 1)

    f32x16 aHH = {}, aHL = {}, aLH = {};
#pragma unroll
    for (int ks = 0; ks < 4; ++ks) {
      aHH = __builtin_amdgcn_mfma_f32_32x32x16_bf16(aH[ks], BH[cur][ks], aHH, 0, 0, 0);
      aHL = __builtin_amdgcn_mfma_f32_32x32x16_bf16(aH[ks], BL[cur][ks], aHL, 0, 0, 0);
      aLH = __builtin_amdgcn_mfma_f32_32x32x16_bf16(aL[ks], BH[cur][ks], aLH, 0, 0, 0);
    }

    float sqc = SQC[cur];
#pragma unroll
    for (int i = 0; i < 16; ++i) {
      float g = (aHH[i] + aHL[i]) + aLH[i];
      float u = (sqr[i] + sqc) - 2.0f * g;
      _Float16 hv = (_Float16)u;
      rowp[i][ct * 32] = __builtin_bit_cast(short, hv);
      float nm2 = fminf(fmaxf(u, m1[i]), m2[i]);
      m1[i] = fminf(u, m1[i]);
      m2[i] = nm2;
    }
  }
#undef LOADB

#pragma unroll
  for (int s = 1; s <= 16; s <<= 1) {
#pragma unroll
    for (int i = 0; i < 16; ++i) {
      float o1 = __shfl_xor(m1[i], s);
      float o2 = __shfl_xor(m2[i], s);
      float n1 = fminf(m1[i], o1);
      float n2 = fminf(fmaxf(m1[i], o1), fminf(m2[i], o2));
      m1[i] = n1;
      m2[i] = n2;
    }
  }
  if (l31 == 0) {
#pragma unroll
    for (int i = 0; i < 16; ++i) {
      int ri = (i & 3) + 8 * (i >> 2) + 4 * h;
      cellA[(size_t)(gr0 + ri) * 16 + cb] = make_float2(m1[i], m2[i]);
    }
  }
}

// ---------------- K4: uthr[row] from 16th-smallest u of cellA union (r16-verified) ----------------
__global__ __launch_bounds__(256) void thr_kernel(
    const float2* __restrict__ cellA, const float* __restrict__ temp,
    float* __restrict__ uthr) {
  int row = (int)blockIdx.x * 256 + (int)threadIdx.x;
  float s32 = (float)exp(fmin(fmax((double)temp[0], -5.0), 5.0));
  const float2* cm = cellA + (size_t)row * 16;
  float tv[16];
#pragma unroll
  for (int k = 0; k < 16; ++k) tv[k] = __builtin_inff();
  for (int i = 0; i < 16; ++i) {
    float2 v2 = cm[i];
#pragma unroll
    for (int j = 0; j < 2; ++j) {
      float v = j ? v2.y : v2.x;
      if (v < tv[15]) {
#pragma unroll
        for (int k = 15; k >= 1; --k) {
          bool ltk = v < tv[k], ltk1 = v < tv[k - 1];
          tv[k] = ltk ? (ltk1 ? tv[k - 1] : v) : tv[k];
        }
        if (v < tv[0]) tv[0] = v;
      }
    }
  }
  float P16 = fmaxf(tv[15], 0.f) * s32;
  float T = P16 + (EPSA + GMINPAD + SCRMARG + EPSA + GMAXF);
  double ud = (double)T / (double)s32;
  float base = (float)(ud * 1.000002 + 1e-6);
  uthr[row] = base + 0.001f * fabsf(base) + 0.002f;
}

// order-preserving f32 -> u32 (lex key with col)
static __device__ __forceinline__ unsigned f2ord(float f) {
  unsigned u = __float_as_uint(f);
  return (u & 0x80000000u) ? ~u : (u | 0x80000000u);
}
static __device__ __forceinline__ float ord2f(unsigned u) {
  unsigned o = (u & 0x80000000u) ? (u & 0x7FFFFFFFu) : ~u;
  return __uint_as_float(o);
}

// ---------------- K5: block-per-row scan + rescore + RANK-BASED parallel top-16 ----------------
__global__ __launch_bounds__(256) void select_kernel(
    const short* __restrict__ ustore, const float* __restrict__ uthra,
    const float* __restrict__ xe, const float* __restrict__ sq,
    const float* __restrict__ temp, const float* __restrict__ q,
    float* __restrict__ e0, float* __restrict__ e1, float* __restrict__ lp) {
#pragma clang fp contract(off)
  __shared__ unsigned short lst_s[CAP];
  __shared__ unsigned long long keys_s[16 + 512];  // [0..15] carry, [16..] chunk
  __shared__ unsigned long long out16_s[16];
  __shared__ float xr_s[DE];
  __shared__ int lcnt_s;

  int t = threadIdx.x;
  int row = (int)blockIdx.x;
  int b = row >> 12, n = row & (NN - 1);
  float s32 = (float)exp(fmin(fmax((double)temp[0], -5.0), 5.0));
  float uthr = uthra[row];
  const unsigned long long KMAX = ~0ULL;

  if (t < DE) xr_s[t] = xe[(size_t)row * DE + t];
  if (t < 16) keys_s[t] = KMAX;  // init carry
  if (t == 0) lcnt_s = 0;
  __syncthreads();

  // phase 1: coalesced scan, LDS-atomic compaction (order-free: keys sort later)
  const short8v* rp16 = (const short8v*)(ustore + (size_t)row * NN);
#pragma unroll
  for (int r = 0; r < 2; ++r) {
    int idx = r * 256 + t;  // short8v index in [0,512)
    short8v v = rp16[idx];
    unsigned m = 0;
#pragma unroll
    for (int c = 0; c < 8; ++c) {
      _Float16 hv = __builtin_bit_cast(_Float16, (short)v[c]);
      m |= (unsigned)((float)hv < uthr) << c;
    }
    while (m) {
      int c = __builtin_ctz(m);
      m &= m - 1;
      int pos = atomicAdd(&lcnt_s, 1);
      if (pos < CAP) lst_s[pos] = (unsigned short)(idx * 8 + c);
    }
  }
  __syncthreads();
  int cnt = lcnt_s;
  bool overflow = cnt > CAP;  // sound fallback: full row scan (cnt >= 16 always)
  int nitems = overflow ? NN : cnt;

  // phase 2: chunks of 512 with 16-key carry; rescore + rank-select
  float sqr = sq[row];
  const float* xb = xe + ((size_t)(b << 12)) * DE;
  const float* sqb = sq + (b << 12);
  const float* qrow = q + ((size_t)b * NN + n) * NN;

  for (int ch0 = 0; ch0 < nitems; ch0 += 512) {
    int m = nitems - ch0;
    if (m > 512) m = 512;
    // rescore chunk items (golden chain, r7-verified) into keys_s[16+i]
#pragma unroll
    for (int rsub = 0; rsub < 2; ++rsub) {
      int li = rsub * 256 + t;
      if (li < m) {
        int gi = ch0 + li;
        int col = overflow ? gi : (int)lst_s[gi];
        const float* xc = xb + (size_t)col * DE;
        float acc = 0.f;
#pragma unroll
        for (int d = 0; d < DE; ++d)
          acc = __builtin_fmaf(xr_s[d], xc[d], acc);  // golden seq-FMA
        float u = (sqr + sqb[col]) - 2.0f * acc;
        float P = fmaxf(u, 0.0f) * s32;
        float qv = qrow[col];
        float t1 = qv + 1e-8f;
        float l1 = (float)log((double)t1);  // CR f32 log (r7-verified)
        float G = (float)log((double)(-l1));
        float lq = P - G;
        keys_s[16 + li] = ((unsigned long long)f2ord(lq) << 32) | (unsigned)col;
      }
    }
    __syncthreads();
    // rank-select: rank_i = #{j: key_j < key_i}; unique keys => perfect placement
    int pool_n = 16 + m;
    for (int base = 0; base < pool_n; base += 256) {
      int i = base + t;
      if (i < pool_n) {
        unsigned long long ki = keys_s[i];
        if (ki != KMAX) {
          int rank = 0;
          for (int j = 0; j < pool_n; ++j) rank += (keys_s[j] < ki) ? 1 : 0;
          if (rank < 16) out16_s[rank] = ki;
        }
      }
    }
    __syncthreads();
    if (t < 16) keys_s[t] = out16_s[t];  // carry for next chunk
    __syncthreads();
  }

  if (t < 16) {
    unsigned long long k = keys_s[t];  // sorted ascending (lq, col)
    float lq = ord2f((unsigned)(k >> 32));
    int col = (int)(unsigned)(k & 0xFFFFFFFFu);
    size_t o = (size_t)row * KK + t;
    lp[o] = -lq;
    e0[o] = (float)(col + b * NN);
    e1[o] = (float)(n + b * NN);
  }
}

extern "C" void kernel_launch(void* const* d_in, const int* in_sizes, int n_in,
                              void* d_out, int out_size, void* d_ws,
                              size_t ws_size, hipStream_t stream) {
  (void)in_sizes; (void)n_in; (void)out_size; (void)ws_size;
  const float* x = (const float*)d_in[0];
  // d_in[1] = A (unused placeholder)
  const float* W = (const float*)d_in[2];
  const float* bias = (const float*)d_in[3];
  const float* temp = (const float*)d_in[4];
  const float* q = (const float*)d_in[5];

  float* xe = (float*)d_out;                 // [4,4096,64]
  float* e0 = xe + (size_t)BATCH * NN * DE;  // edges row 0 (indices)
  float* e1 = e0 + (size_t)BATCH * NN * KK;  // edges row 1 (rows)
  float* lp = e1 + (size_t)BATCH * NN * KK;  // logprobs

  const int ROWS = BATCH * NN;  // 16384
  char* ws = (char*)d_ws;
  float* sq = (float*)ws;                                  // 64 KB
  float* uthr = (float*)(ws + (64 << 10));                 // 64 KB
  float2* cellA = (float2*)(ws + (128 << 10));             // 2 MB
  char* p = ws + (128 << 10) + (size_t)ROWS * 16 * 8;
  __hip_bfloat16* xeH = (__hip_bfloat16*)p;                // 2 MB
  __hip_bfloat16* xeL = (__hip_bfloat16*)(p + (size_t)ROWS * DE * 2);  // 2 MB
  short* ustore = (short*)(p + 2 * (size_t)ROWS * DE * 2); // 128 MB
  // total ~134 MB; ws_size proven >= 1 GiB (harness 0xAA fill)

  embed_kernel<<<BATCH * NN / 4, 256, 0, stream>>>(x, W, bias, xe, xeH, xeL);
  sqnorm_kernel<<<ROWS / 256, 256, 0, stream>>>(xe, sq);
  mfma_passA_kernel<<<BATCH * 32 * 16, 256, 0, stream>>>(xeH, xeL, sq, cellA,
                                                         ustore);
  thr_kernel<<<ROWS / 256, 256, 0, stream>>>(cellA, temp, uthr);
  select_kernel<<<ROWS, 256, 0, stream>>>(ustore, uthr, xe, sq, temp, q, e0, e1,
                                          lp);
}